// Round 11
// baseline (140.977 us; speedup 1.0000x reference)
//
#include <hip/hip_runtime.h>

// Attention, 20 slices of [N=1024, D=256]. R15: 64-row q-tiles, Q fully in
// registers. Model fitted across R7/R11/R12/R14 (all within ~8%): makespan =
// (max blocks/CU) x (per-block max-pipe cyc/kt) x 16 x ~2.2, pipes = L1
// 64B/cyc and LDS 128B/cyc. This design: 320 blocks (max 2/CU), per-block-kt
// L1 32KB (vf only, 500cy) / LDS 144KB (K dma-w 32 + af-r 32 + P-w 16 +
// pf-r 64, 1125cy) -> pred ~33us vs R12's 2000cy/44us. R11 tried 64-row but
// leaked 96KB/kt Q-LDS reads (208KB total -> null, now explained); Q-in-regs
// (qf[4][8]=128 VGPR) removes the leak. Register ceiling forces PV db-outer
// with pf re-read and vf half-prefetch (16 regs): peak ~192 arch + 64 AGPR.
// Sync skeleton unchanged from R7/R12: counted vmcnt(4) top-wait (kdma x8
// oldest, vf0 x4 newer), ONE lgkm-only barrier per kt, P dbuf, wave-private
// K staging (wave reads only rows it DMA'd).

typedef __attribute__((ext_vector_type(8))) short bf16x8;
typedef __attribute__((ext_vector_type(4))) float f32x4;
typedef __attribute__((ext_vector_type(16))) float f32x16;

#define GLD16(gp, lp) __builtin_amdgcn_global_load_lds( \
    (const __attribute__((address_space(1))) unsigned int*)(const void*)(gp), \
    (__attribute__((address_space(3))) unsigned int*)(void*)(lp), 16, 0, 0)

// LDS-only barrier: no vmcnt drain (K-DMA + vf global loads stay in flight)
#define LDS_BARRIER() __asm__ volatile("s_waitcnt lgkmcnt(0)\ns_barrier" ::: "memory")
#define MEMFENCE()    __asm__ volatile("" ::: "memory")
// wait the 8 oldest VMEM ops (this wave's K-DMA); 4 newer vf0 loads keep flying
#define WAIT_KDMA()   do { __asm__ volatile("s_waitcnt vmcnt(4)" ::: "memory"); \
                           __builtin_amdgcn_sched_barrier(0); } while (0)

__device__ __forceinline__ unsigned int pack_bf16_rne(float a, float b) {
    unsigned int ua = __float_as_uint(a); ua += 0x7FFFu + ((ua >> 16) & 1u);
    unsigned int ub = __float_as_uint(b); ub += 0x7FFFu + ((ub >> 16) & 1u);
    return (ua >> 16) | (ub & 0xFFFF0000u);
}
__device__ __forceinline__ unsigned int pack2_trunc(float lo, float hi) {
    return __builtin_amdgcn_perm(__float_as_uint(hi), __float_as_uint(lo), 0x07060302u);
}

// Fused prep (unchanged): bid<640 -> XV tiles, else -> XT tiles.
// XT[slice][n][chunk^(n&7)] bf16.  XV[slice][cc=m>>3][d][j=m&7] bf16.
__global__ __launch_bounds__(256) void prep_kernel(const float* __restrict__ x,
                                                   unsigned short* __restrict__ XT,
                                                   unsigned short* __restrict__ XV) {
    __shared__ __align__(16) unsigned char smem[16384];
    int bid = blockIdx.x;
    int t = threadIdx.x;
    if (bid < 640) {
        uint4* T = (uint4*)smem;                      // [32cc][32d'] 16KB
        int slice = bid >> 5, w = bid & 31;
        int cc0 = (w & 3) * 32, d0 = (w >> 2) * 32;
        const float* xs = x + slice * 262144;
        int ccl = t & 31, dr = t >> 5;
        #pragma unroll
        for (int p = 0; p < 4; ++p) {
            int dl = p * 8 + dr;
            const float* src = xs + (d0 + dl) * 1024 + (cc0 + ccl) * 8;
            float4 a = *(const float4*)(src);
            float4 b = *(const float4*)(src + 4);
            uint4 o;
            o.x = pack_bf16_rne(a.x, a.y); o.y = pack_bf16_rne(a.z, a.w);
            o.z = pack_bf16_rne(b.x, b.y); o.w = pack_bf16_rne(b.z, b.w);
            T[ccl * 32 + (dl ^ ccl)] = o;
        }
        __syncthreads();
        unsigned short* xv = XV + slice * 262144;
        int dl2 = t & 31, cr = t >> 5;
        #pragma unroll
        for (int p = 0; p < 4; ++p) {
            int ccl2 = p * 8 + cr;
            uint4 o = T[ccl2 * 32 + (dl2 ^ ccl2)];
            *(uint4*)(xv + ((cc0 + ccl2) * 256 + d0 + dl2) * 8) = o;
        }
    } else {
        unsigned long long* TX = (unsigned long long*)smem;   // [64n][32dq] 16KB
        int b = bid - 640;
        int slice = b >> 5, w = b & 31;
        int d0 = (w & 1) * 128, n0 = (w >> 1) * 64;
        const float* xs = x + slice * 262144;
        int nq = t & 15, dqh = t >> 4;
        #pragma unroll
        for (int p = 0; p < 2; ++p) {
            int dq = p * 16 + dqh;
            const float* src = xs + (d0 + dq * 4) * 1024 + n0 + nq * 4;
            float4 r0 = *(const float4*)(src);
            float4 r1 = *(const float4*)(src + 1024);
            float4 r2 = *(const float4*)(src + 2048);
            float4 r3 = *(const float4*)(src + 3072);
            const float* f0 = (const float*)&r0; const float* f1 = (const float*)&r1;
            const float* f2 = (const float*)&r2; const float* f3 = (const float*)&r3;
            #pragma unroll
            for (int j = 0; j < 4; ++j) {
                int nl2 = nq * 4 + j;
                unsigned long long q = (unsigned long long)pack_bf16_rne(f0[j], f1[j])
                    | ((unsigned long long)pack_bf16_rne(f2[j], f3[j]) << 32);
                TX[nl2 * 32 + (dq ^ (nl2 & 31))] = q;
            }
        }
        __syncthreads();
        unsigned short* xt = XT + slice * 262144;
        int ch = t & 15, nr = t >> 4;
        #pragma unroll
        for (int p = 0; p < 4; ++p) {
            int nl2 = p * 16 + nr;
            unsigned long long qlo = TX[nl2 * 32 + ((ch * 2) ^ (nl2 & 31))];
            unsigned long long qhi = TX[nl2 * 32 + ((ch * 2 + 1) ^ (nl2 & 31))];
            uint4 o = make_uint4((unsigned int)qlo, (unsigned int)(qlo >> 32),
                                 (unsigned int)qhi, (unsigned int)(qhi >> 32));
            *(uint4*)(xt + (n0 + nl2) * 256 + ((((d0 >> 3) + ch) ^ (nl2 & 7)) * 8)) = o;
        }
    }
}

__global__ __launch_bounds__(256, 2) void attn_kernel(const unsigned short* __restrict__ XT,
                                                      const unsigned short* __restrict__ XV,
                                                      const int* __restrict__ beta,
                                                      float* __restrict__ out) {
    __shared__ __align__(16) unsigned short Kmd[64 * 256];    // 32KB K-tile, wave-private rows
    __shared__ __align__(16) unsigned short Pb[2][64 * 64];   // P dbuf [buf][64n][64m], 16KB
    __shared__ float Lpart[4][64];
    __shared__ __align__(16) float Ltot[64];

    int bid = blockIdx.x;
    int t = ((bid & 7) * 40) + (bid >> 3);      // XCD swizzle (320 blocks)
    int slice = t >> 4, qh = t & 15;            // qh: 64-row q-tile

    int tid = threadIdx.x;
    int lane = tid & 63, wv = tid >> 6;         // 4 waves
    int nl = lane & 15, g = lane >> 4;          // 16x16 frame
    int lo = lane & 31, hi = lane >> 5;         // 32x32 frame

    const unsigned short* xt_s = XT + slice * 262144;
    const unsigned short* xv_s = XV + slice * 262144;
    float cscale = (float)(beta[0]) * 1.44269504089f;   // beta * log2(e)

    auto kdma = [&](int kt) {                   // wave-private: own 8 chunks = own 16 m-rows
        const unsigned short* gk = xt_s + kt * 16384;
        #pragma unroll
        for (int i = 0; i < 8; ++i) {
            int ch = wv * 8 + i;
            GLD16(gk + ch * 512 + lane * 8, &Kmd[ch * 512]);
        }
    };

    // ---- prologue: K-DMA(0) FIRST (oldest in vm queue) ----
    kdma(0);
    MEMFENCE();

    // ---- Q fragments: ALL 4 strips in regs + fixed softmax max ----
    bf16x8 qf[4][8];                            // 128 VGPRs
    float mcol[4];
    #pragma unroll
    for (int st = 0; st < 4; ++st) {
        int n = qh * 64 + st * 16 + nl;
        const unsigned short* qrow = xt_s + n * 256;
        float dg = 0.f;
        #pragma unroll
        for (int ks = 0; ks < 8; ++ks) {
            qf[st][ks] = *(const bf16x8*)(qrow + (((ks * 4 + g) ^ (n & 7)) * 8));
            const unsigned int* qu = (const unsigned int*)&qf[st][ks];
            #pragma unroll
            for (int w = 0; w < 4; ++w) {
                float flo = __uint_as_float(qu[w] << 16);
                float fhi = __uint_as_float(qu[w] & 0xFFFF0000u);
                dg = fmaf(flo, flo, dg);
                dg = fmaf(fhi, fhi, dg);
            }
        }
        dg += __shfl_xor(dg, 16);
        dg += __shfl_xor(dg, 32);
        mcol[st] = dg * cscale;   // consumes qf loads -> retired; K-DMA stays out
    }

    f32x16 acc[2][2];                // O[nb*32.. n][wv*64 + db*32 + lo]
    acc[0][0] = (f32x16)(0.f); acc[0][1] = (f32x16)(0.f);
    acc[1][0] = (f32x16)(0.f); acc[1][1] = (f32x16)(0.f);
    float lac[4] = {0.f, 0.f, 0.f, 0.f};

    // vf cells: cc = kt*8 + ks*2 + hi, d = wv*64 + db*32 + lo; db -> +256 shorts
    const unsigned short* vb = xv_s + (hi * 256 + wv * 64 + lo) * 8;
    bf16x8 vf0[4];                   // db=0 half, prefetched 1 kt ahead (16 regs)
    MEMFENCE();
    #pragma unroll
    for (int ks = 0; ks < 4; ++ks) vf0[ks] = *(const bf16x8*)(vb + ks * 4096);
    // vm queue at loop top: [kdma(kt) x8 oldest][vf0(kt) x4 newest] -> vmcnt(4)

    const unsigned short* kmd_row = &Kmd[(wv * 16 + nl) * 256];

    for (int kt = 0; kt < 16; ++kt) {
        WAIT_KDMA();                 // vmcnt(4): Kmd(kt) landed; vf0(kt) flying

        // ---- S(kt): own 16m x all 64n (af reused across 4 strips) ----
        f32x4 s0 = {0.f,0.f,0.f,0.f}, s1 = {0.f,0.f,0.f,0.f};
        f32x4 s2 = {0.f,0.f,0.f,0.f}, s3 = {0.f,0.f,0.f,0.f};
        #pragma unroll
        for (int ks = 0; ks < 8; ++ks) {
            bf16x8 af = *(const bf16x8*)(kmd_row + (((ks * 4 + g) ^ (nl & 7)) * 8));
            s0 = __builtin_amdgcn_mfma_f32_16x16x32_bf16(af, qf[0][ks], s0, 0, 0, 0);
            s1 = __builtin_amdgcn_mfma_f32_16x16x32_bf16(af, qf[1][ks], s1, 0, 0, 0);
            s2 = __builtin_amdgcn_mfma_f32_16x16x32_bf16(af, qf[2][ks], s2, 0, 0, 0);
            s3 = __builtin_amdgcn_mfma_f32_16x16x32_bf16(af, qf[3][ks], s3, 0, 0, 0);
        }

        // ---- softmax (fixed max) + P write, 4 strips -> Pb[kt&1] ----
        {
            f32x4 sv[4] = {s0, s1, s2, s3};
            #pragma unroll
            for (int st = 0; st < 4; ++st) {
                float p0 = exp2f(fmaf(sv[st][0], cscale, -mcol[st]));
                float p1 = exp2f(fmaf(sv[st][1], cscale, -mcol[st]));
                float p2 = exp2f(fmaf(sv[st][2], cscale, -mcol[st]));
                float p3 = exp2f(fmaf(sv[st][3], cscale, -mcol[st]));
                lac[st] += (p0 + p1) + (p2 + p3);
                *(uint2*)(&Pb[kt & 1][(st * 16 + nl) * 64 +
                                      (((wv * 2 + (g >> 1)) ^ (nl & 7)) * 8) + (g & 1) * 4]) =
                    make_uint2(pack2_trunc(p0, p1), pack2_trunc(p2, p3));
            }
        }

        // restage own Kmd rows for kt+1 (af reads consumed by S MFMAs above)
        if (kt < 15) kdma(kt + 1);
        MEMFENCE();

        LDS_BARRIER();               // the ONLY barrier per kt: P(kt) visible

        // ---- PV(kt): O[64n x 64d] += P[64n x 64m] * V[64m x 64d], db-outer ----
        {
            const unsigned short* vcur = vb + kt * 16384;
            const unsigned short* vnxt = vb + (kt + 1) * 16384;
            // JIT-issue db=1 half (flight hidden under db=0 MFMAs)
            bf16x8 vf1[4];
            #pragma unroll
            for (int ks = 0; ks < 4; ++ks) vf1[ks] = *(const bf16x8*)(vcur + ks * 4096 + 256);
            // db = 0 (vf0 prefetched last iteration)
            #pragma unroll
            for (int ks = 0; ks < 4; ++ks) {
                int ch = ((ks * 2 + hi) ^ (lo & 7)) * 8;
                bf16x8 pf0 = *(const bf16x8*)(&Pb[kt & 1][lo * 64 + ch]);
                bf16x8 pf1 = *(const bf16x8*)(&Pb[kt & 1][(32 + lo) * 64 + ch]);
                acc[0][0] = __builtin_amdgcn_mfma_f32_32x32x16_bf16(pf0, vf0[ks], acc[0][0], 0, 0, 0);
                acc[1][0] = __builtin_amdgcn_mfma_f32_32x32x16_bf16(pf1, vf0[ks], acc[1][0], 0, 0, 0);
            }
            // prefetch vf0 for kt+1 (flight = db1 MFMAs + next S + softmax)
            if (kt < 15) {
                #pragma unroll
                for (int ks = 0; ks < 4; ++ks) vf0[ks] = *(const bf16x8*)(vnxt + ks * 4096);
            }
            // db = 1 (vf1 JIT; compiler-counted wait)
            #pragma unroll
            for (int ks = 0; ks < 4; ++ks) {
                int ch = ((ks * 2 + hi) ^ (lo & 7)) * 8;
                bf16x8 pf0 = *(const bf16x8*)(&Pb[kt & 1][lo * 64 + ch]);
                bf16x8 pf1 = *(const bf16x8*)(&Pb[kt & 1][(32 + lo) * 64 + ch]);
                acc[0][1] = __builtin_amdgcn_mfma_f32_32x32x16_bf16(pf0, vf1[ks], acc[0][1], 0, 0, 0);
                acc[1][1] = __builtin_amdgcn_mfma_f32_32x32x16_bf16(pf1, vf1[ks], acc[1][1], 0, 0, 0);
            }
        }
        // vm queue at loop top: [kdma(kt+1) x8 oldest][vf0(kt+1) x4] -> vmcnt(4)
    }

    // ---- epilogue: softmax denominators, scale, store ----
    #pragma unroll
    for (int st = 0; st < 4; ++st) {
        lac[st] += __shfl_xor(lac[st], 16);
        lac[st] += __shfl_xor(lac[st], 32);
    }
    if (lane < 16) {
        #pragma unroll
        for (int st = 0; st < 4; ++st) Lpart[wv][st * 16 + nl] = lac[st];
    }
    LDS_BARRIER();
    if (tid < 64)
        Ltot[tid] = 1.f / (Lpart[0][tid] + Lpart[1][tid] + Lpart[2][tid] + Lpart[3][tid]);
    LDS_BARRIER();

    float* outs = out + slice * 262144 + (qh * 64) * 256;
    #pragma unroll
    for (int nb = 0; nb < 2; ++nb) {
        #pragma unroll
        for (int rq = 0; rq < 4; ++rq) {
            f32x4 li = *(const f32x4*)(&Ltot[nb * 32 + rq * 8 + hi * 4]);
            #pragma unroll
            for (int j = 0; j < 4; ++j) {
                int row = nb * 32 + rq * 8 + hi * 4 + j;
                #pragma unroll
                for (int db = 0; db < 2; ++db)
                    outs[row * 256 + wv * 64 + db * 32 + lo] = acc[nb][db][rq * 4 + j] * li[j];
            }
        }
    }
}

extern "C" void kernel_launch(void* const* d_in, const int* in_sizes, int n_in,
                              void* d_out, int out_size, void* d_ws, size_t ws_size,
                              hipStream_t stream) {
    const float* x = (const float*)d_in[0];
    const int* beta = (const int*)d_in[1];
    float* out = (float*)d_out;
    unsigned short* XT = (unsigned short*)d_ws;                 // 10,485,760 B
    unsigned short* XV = (unsigned short*)d_ws + 5242880;       // 10,485,760 B
    prep_kernel<<<1280, 256, 0, stream>>>(x, XT, XV);
    attn_kernel<<<320, 256, 0, stream>>>(XT, XV, beta, out);
}